// Round 18
// baseline (93.508 us; speedup 1.0000x reference)
//
#include <hip/hip_runtime.h>
#include <hip/hip_cooperative_groups.h>

namespace cg = cooperative_groups;

#define Bq 2
#define Nq 1024
#define Cq 128
#define Eq 64
#define Kq 20
#define BN (Bq * Nq)
#define BNK (BN * Kq)
#define NEGF (-3.0e38f)

#define DPP_F(x, ctrl) __int_as_float(__builtin_amdgcn_update_dpp( \
    __float_as_int(x), __float_as_int(x), (ctrl), 0xf, 0xf, false))
#define DPP_I(x, ctrl) __builtin_amdgcn_update_dpp((x), (x), (ctrl), 0xf, 0xf, false)
#define RL_F(x, l) __int_as_float(__builtin_amdgcn_readlane(__float_as_int(x), (l)))
#define RL_I(x, l) __builtin_amdgcn_readlane((x), (l))
#define QP_XOR1 0xB1   // quad_perm [1,0,3,2]
#define QP_XOR2 0x4E   // quad_perm [2,3,0,1]
#define ROR4    0x124  // row_ror:4
#define ROR8    0x128  // row_ror:8

// ============ ONE cooperative kernel: proj -> grid.sync -> score+topk ============
// grid = 256 blocks x 512 threads (1 block/CU guaranteed co-resident).
// Removes the proj->attn dispatch boundary (kernel-end L2 writeback + L1 invalidate +
// wave drain/relaunch) — the per-dispatch transient identified as the ~30us invariant.
__global__ __launch_bounds__(512) void fused_kernel(
    const float* __restrict__ x, const float* __restrict__ Wl,
    const float* __restrict__ bl, const float* __restrict__ Wr,
    const float* __restrict__ br, const float* __restrict__ att,
    float* __restrict__ xl, float* __restrict__ xrP, float* __restrict__ rdot,
    float* __restrict__ out) {
  const int tid  = threadIdx.x;
  const int lane = tid & 63;
  const int wave = tid >> 6;

  __shared__ float xs[8][Cq];      // 4 KB (phase A staging)
  __shared__ float alpha[4][Nq];   // 16 KB (phase B scores)

  // ---------------- Phase A: proj for this block's 8 rows ----------------
  // wave r owns row (blockIdx*8 + r); lane = e. Same FP order as R11 proj.
  {
    const int idx = tid * 2;                       // stage 8x128 x-rows as float2
    const float2 v = *(const float2*)&x[(size_t)blockIdx.x * 8 * Cq + idx];
    xs[idx >> 7][idx & 127] = v.x;
    xs[idx >> 7][(idx & 127) + 1] = v.y;           // idx even -> same row
  }
  __syncthreads();
  {
    const int r = wave;                            // 8 waves = 8 rows
    const int e = lane;
    const int row = blockIdx.x * 8 + r;
    float accL = 0.f, accR = 0.f;
#pragma unroll 8
    for (int c = 0; c < Cq; ++c) {
      const float xv = xs[r][c];
      accL = fmaf(xv, Wl[c * Eq + e], accL);
      accR = fmaf(xv, Wr[c * Eq + e], accR);
    }
    accL += bl[e];
    accR += br[e];
    xl[(size_t)row * Eq + e] = accL;
    // plane-major: xrP[ch=e>>2][row][c=e&3]
    xrP[((size_t)(e >> 2) * BN + row) * 4 + (e & 3)] = accR;
    float s = accR * att[e];                       // rdot[row]
    s += DPP_F(s, QP_XOR1);
    s += DPP_F(s, QP_XOR2);
    s += DPP_F(s, ROR4);
    s += DPP_F(s, ROR8);
    const float sd = (RL_F(s, 0) + RL_F(s, 16)) + (RL_F(s, 32) + RL_F(s, 48));
    if (e == 0) rdot[row] = sd;
  }

  // ---------------- grid-wide sync (agent-scope fence: xrP/xl/rdot visible) ----------------
  cg::this_grid().sync();

  // ---------------- Phase B: two TI=4 row-groups, R11-verbatim core ----------------
#pragma unroll 1
  for (int g = 0; g < 2; ++g) {
    const int r0g = blockIdx.x * 8 + g * 4;
    const int b   = r0g >> 10;

    // ---- phase-1: V_C core (4 rows x 2 j, 1-ahead pipeline) ----
    {
      const int jt = tid;
      const float* __restrict__ xlw = xl + (size_t)r0g * Eq;  // block-uniform

      const float rd0 = 1.5f * rdot[b * Nq + jt];
      const float rd1 = 1.5f * rdot[b * Nq + jt + 512];
      float acc[4][2];
#pragma unroll
      for (int r = 0; r < 4; ++r) { acc[r][0] = rd0; acc[r][1] = rd1; }

      const float* __restrict__ vb = xrP + (size_t)(b * Nq + jt) * 4;
      float4 nv0 = *(const float4*)(vb);
      float4 nv1 = *(const float4*)(vb + 512 * 4);
      float4 na0 = *(const float4*)(xlw);
      float4 na1 = *(const float4*)(xlw + Eq);
      float4 na2 = *(const float4*)(xlw + 2 * Eq);
      float4 na3 = *(const float4*)(xlw + 3 * Eq);
      float4 nat = *(const float4*)(att);

#pragma unroll
      for (int ch = 0; ch < 16; ++ch) {
        const float4 v0 = nv0, v1 = nv1;
        const float4 a0 = na0, a1 = na1, a2 = na2, a3 = na3, at = nat;
        if (ch < 15) {
          vb += BN * 4;
          nv0 = *(const float4*)(vb);
          nv1 = *(const float4*)(vb + 512 * 4);
          na0 = *(const float4*)(xlw + (ch + 1) * 4);
          na1 = *(const float4*)(xlw + Eq + (ch + 1) * 4);
          na2 = *(const float4*)(xlw + 2 * Eq + (ch + 1) * 4);
          na3 = *(const float4*)(xlw + 3 * Eq + (ch + 1) * 4);
          nat = *(const float4*)(att + (ch + 1) * 4);
        }
        const float* v0p = (const float*)&v0;
        const float* v1p = (const float*)&v1;
        const float* a0p = (const float*)&a0;
        const float* a1p = (const float*)&a1;
        const float* a2p = (const float*)&a2;
        const float* a3p = (const float*)&a3;
        const float* atp = (const float*)&at;
#pragma unroll
        for (int dd = 0; dd < 4; ++dd) {
          const float a = atp[dd];
          const float x0 = v0p[dd], x1 = v1p[dd];
          acc[0][0] = fmaf(fabsf(a0p[dd] + x0), a, acc[0][0]);
          acc[0][1] = fmaf(fabsf(a0p[dd] + x1), a, acc[0][1]);
          acc[1][0] = fmaf(fabsf(a1p[dd] + x0), a, acc[1][0]);
          acc[1][1] = fmaf(fabsf(a1p[dd] + x1), a, acc[1][1]);
          acc[2][0] = fmaf(fabsf(a2p[dd] + x0), a, acc[2][0]);
          acc[2][1] = fmaf(fabsf(a2p[dd] + x1), a, acc[2][1]);
          acc[3][0] = fmaf(fabsf(a3p[dd] + x0), a, acc[3][0]);
          acc[3][1] = fmaf(fabsf(a3p[dd] + x1), a, acc[3][1]);
        }
      }
#pragma unroll
      for (int r = 0; r < 4; ++r) {
        alpha[r][jt]       = acc[r][0];
        alpha[r][jt + 512] = acc[r][1];
      }
    }
    __syncthreads();

    // ---- phase-2: waves 0..3 = top-K of row (r0g+wave), DPP-only ----
    if (wave < 4) {
      float vals[16];
#pragma unroll
      for (int s = 0; s < 16; ++s) vals[s] = alpha[wave][lane + 64 * s];

      float lv = vals[0];
      int   pk = lane;                    // pk = (s<<6)|lane == j
#pragma unroll
      for (int s = 1; s < 16; ++s)
        if (vals[s] > lv) { lv = vals[s]; pk = (s << 6) | lane; }

      float m0 = 0.f, ssum = 0.f, myv = 0.f;
      int myi = 0;
#pragma unroll 1
      for (int round = 0; round < Kq; ++round) {
        float m = lv;
        m = fmaxf(m, DPP_F(m, QP_XOR1));
        m = fmaxf(m, DPP_F(m, QP_XOR2));
        m = fmaxf(m, DPP_F(m, ROR4));
        m = fmaxf(m, DPP_F(m, ROR8));
        const float bv = fmaxf(fmaxf(RL_F(m, 0), RL_F(m, 16)),
                               fmaxf(RL_F(m, 32), RL_F(m, 48)));
        int key = (lv == bv) ? pk : 0x7FFFFFFF;   // min-j tie-break (lax.top_k)
        key = min(key, DPP_I(key, QP_XOR1));
        key = min(key, DPP_I(key, QP_XOR2));
        key = min(key, DPP_I(key, ROR4));
        key = min(key, DPP_I(key, ROR8));
        const int jsel = min(min(RL_I(key, 0), RL_I(key, 16)),
                             min(RL_I(key, 32), RL_I(key, 48)));
        if (round == 0) m0 = bv;
        ssum += __expf(0.4f * (bv - m0));
        if (lane == round) { myv = bv; myi = jsel; }
        if (lane == (jsel & 63)) {
          const int sk = jsel >> 6;
#pragma unroll
          for (int s = 0; s < 16; ++s)
            if (s == sk) vals[s] = NEGF;
          lv = vals[0]; pk = lane;
#pragma unroll
          for (int s = 1; s < 16; ++s)
            if (vals[s] > lv) { lv = vals[s]; pk = (s << 6) | lane; }
        }
      }

      if (lane < Kq) {
        const int gi = r0g + wave;
        const float p = __expf(0.4f * (myv - m0)) / ssum;
        const int base = gi * Kq + lane;
        out[base]            = (float)gi;              // index_i
        out[BNK + base]      = (float)(b * Nq + myi);  // index_j
        out[2 * BNK + base]  = p;                      // attention
      }
    }
    __syncthreads();   // alpha reused by next g
  }
}

extern "C" void kernel_launch(void* const* d_in, const int* in_sizes, int n_in,
                              void* d_out, int out_size, void* d_ws, size_t ws_size,
                              hipStream_t stream) {
  const float* x   = (const float*)d_in[0];
  const float* Wl  = (const float*)d_in[1];
  const float* bl  = (const float*)d_in[2];
  const float* Wr  = (const float*)d_in[3];
  const float* br  = (const float*)d_in[4];
  const float* att = (const float*)d_in[5];
  float* out = (float*)d_out;

  float* xl   = (float*)d_ws;                    // [B*N, E]
  float* xrP  = xl + (size_t)BN * Eq;            // [16][B*N][4] plane-major
  float* rdot = xrP + (size_t)16 * BN * 4;       // [B*N]

  void* args[] = {(void*)&x, (void*)&Wl, (void*)&bl, (void*)&Wr, (void*)&br,
                  (void*)&att, (void*)&xl, (void*)&xrP, (void*)&rdot, (void*)&out};
  hipLaunchCooperativeKernel((const void*)fused_kernel, dim3(BN / 8), dim3(512),
                             args, 0, stream);
}

// Round 19
// 50.085 us; speedup vs baseline: 1.8670x; 1.8670x over previous
//
#include <hip/hip_runtime.h>

#define Bq 2
#define Nq 1024
#define Cq 128
#define Eq 64
#define Kq 20
#define T4 4               // j-tiles per row
#define JT (Nq / T4)       // 256 j per tile
#define CAND (T4 * Kq)     // 80 candidates per row
#define BN (Bq * Nq)
#define BNK (BN * Kq)
#define NEGF (-3.0e38f)

#define DPP_F(x, ctrl) __int_as_float(__builtin_amdgcn_update_dpp( \
    __float_as_int(x), __float_as_int(x), (ctrl), 0xf, 0xf, false))
#define DPP_I(x, ctrl) __builtin_amdgcn_update_dpp((x), (x), (ctrl), 0xf, 0xf, false)
#define RL_F(x, l) __int_as_float(__builtin_amdgcn_readlane(__float_as_int(x), (l)))
#define RL_I(x, l) __builtin_amdgcn_readlane((x), (l))
#define QP_XOR1 0xB1   // quad_perm [1,0,3,2]
#define QP_XOR2 0x4E   // quad_perm [2,3,0,1]
#define ROR4    0x124  // row_ror:4
#define ROR8    0x128  // row_ror:8

// wave max (uniform result across lanes)
__device__ __forceinline__ float wave_max(float m) {
  m = fmaxf(m, DPP_F(m, QP_XOR1));
  m = fmaxf(m, DPP_F(m, QP_XOR2));
  m = fmaxf(m, DPP_F(m, ROR4));
  m = fmaxf(m, DPP_F(m, ROR8));
  return fmaxf(fmaxf(RL_F(m, 0), RL_F(m, 16)), fmaxf(RL_F(m, 32), RL_F(m, 48)));
}
__device__ __forceinline__ int wave_min_i(int key) {
  key = min(key, DPP_I(key, QP_XOR1));
  key = min(key, DPP_I(key, QP_XOR2));
  key = min(key, DPP_I(key, ROR4));
  key = min(key, DPP_I(key, ROR8));
  return min(min(RL_I(key, 0), RL_I(key, 16)), min(RL_I(key, 32), RL_I(key, 48)));
}

// ---------------- proj: R11-exact ----------------
__global__ __launch_bounds__(128) void proj_kernel(
    const float* __restrict__ x, const float* __restrict__ Wl,
    const float* __restrict__ bl, const float* __restrict__ Wr,
    const float* __restrict__ br, const float* __restrict__ att,
    float* __restrict__ xl, float* __restrict__ xrP, float* __restrict__ rdot) {
  const int row = blockIdx.x;
  const int t = threadIdx.x;
  const int e = t & 63;
  const bool left = (t < 64);
  __shared__ float xs[Cq];
  xs[t] = x[(size_t)row * Cq + t];
  __syncthreads();
  const float* __restrict__ W = left ? Wl : Wr;
  float acc = 0.f;
#pragma unroll 8
  for (int c = 0; c < Cq; ++c) acc = fmaf(xs[c], W[c * Eq + e], acc);
  acc += left ? bl[e] : br[e];
  if (left) {
    xl[(size_t)row * Eq + e] = acc;
  } else {
    xrP[((size_t)(e >> 2) * BN + row) * 4 + (e & 3)] = acc;
    float s = acc * att[e];
    s += DPP_F(s, QP_XOR1);
    s += DPP_F(s, QP_XOR2);
    s += DPP_F(s, ROR4);
    s += DPP_F(s, ROR8);
    const float sd = (RL_F(s, 0) + RL_F(s, 16)) + (RL_F(s, 32) + RL_F(s, 48));
    if (e == 0) rdot[row] = sd;
  }
}

// ---------------- stage 1: per-(4-rows, j-tile) scores + per-tile top-20 ----------------
// grid = (BN/4)*T4 = 2048 blocks, block = 256 (4 waves; wave = row).
// Per-block reads: 64KB xr tile + 1KB xl + 1KB rdot — 4x smaller footprint than before.
__global__ __launch_bounds__(256) void score1_kernel(
    const float* __restrict__ xl, const float* __restrict__ xrP,
    const float* __restrict__ rdot, const float* __restrict__ att,
    float* __restrict__ candV, int* __restrict__ candI) {
  const int bid  = blockIdx.x;
  const int ig   = bid >> 2;
  const int t    = bid & 3;
  const int row  = ig * 4 + (threadIdx.x >> 6);
  const int b    = row >> 10;
  const int lane = threadIdx.x & 63;
  const int j0   = t * JT;                  // batch-local tile base
  const int jbase = b * Nq + j0 + lane;

  // ---- scores for 4 cells: j = j0 + lane + 64*s ----
  float vals[4];
  {
    float acc0 = 1.5f * rdot[jbase];
    float acc1 = 1.5f * rdot[jbase + 64];
    float acc2 = 1.5f * rdot[jbase + 128];
    float acc3 = 1.5f * rdot[jbase + 192];
    const float* __restrict__ xlr = xl + (size_t)row * Eq;
    const float* __restrict__ vb  = xrP + (size_t)jbase * 4;
    float4 n0 = *(const float4*)(vb);
    float4 n1 = *(const float4*)(vb + 64 * 4);
    float4 n2 = *(const float4*)(vb + 128 * 4);
    float4 n3 = *(const float4*)(vb + 192 * 4);
#pragma unroll
    for (int ch = 0; ch < 16; ++ch) {
      const float4 v0 = n0, v1 = n1, v2 = n2, v3 = n3;
      if (ch < 15) {                       // 1-ahead pipeline
        vb += (size_t)BN * 4;
        n0 = *(const float4*)(vb);
        n1 = *(const float4*)(vb + 64 * 4);
        n2 = *(const float4*)(vb + 128 * 4);
        n3 = *(const float4*)(vb + 192 * 4);
      }
      const float4 at4 = *(const float4*)(att + ch * 4);
      const float4 xl4 = *(const float4*)(xlr + ch * 4);
      const float* v0p = (const float*)&v0;
      const float* v1p = (const float*)&v1;
      const float* v2p = (const float*)&v2;
      const float* v3p = (const float*)&v3;
      const float* ap  = (const float*)&at4;
      const float* xp  = (const float*)&xl4;
#pragma unroll
      for (int dd = 0; dd < 4; ++dd) {
        const float a = ap[dd], xd = xp[dd];
        acc0 = fmaf(fabsf(xd + v0p[dd]), a, acc0);
        acc1 = fmaf(fabsf(xd + v1p[dd]), a, acc1);
        acc2 = fmaf(fabsf(xd + v2p[dd]), a, acc2);
        acc3 = fmaf(fabsf(xd + v3p[dd]), a, acc3);
      }
    }
    vals[0] = acc0; vals[1] = acc1; vals[2] = acc2; vals[3] = acc3;
  }

  // ---- per-tile top-20 knockout (exact (val desc, j asc) order) ----
  float lv = vals[0];
  int   pj = j0 + lane;                    // batch-local j of local best
#pragma unroll
  for (int s = 1; s < 4; ++s)
    if (vals[s] > lv) { lv = vals[s]; pj = j0 + lane + (s << 6); }

  float myv = 0.f;
  int myj = 0;
#pragma unroll 1
  for (int round = 0; round < Kq; ++round) {
    const float bv = wave_max(lv);
    const int jsel = wave_min_i((lv == bv) ? pj : 0x7FFFFFFF);
    if (lane == round) { myv = bv; myj = jsel; }
    const int jl = jsel - j0;              // local 0..255
    if ((jl & 63) == lane) {               // owner knockout + rescan (static idx)
      const int sk = jl >> 6;
#pragma unroll
      for (int s = 0; s < 4; ++s)
        if (s == sk) vals[s] = NEGF;
      lv = vals[0]; pj = j0 + lane;
#pragma unroll
      for (int s = 1; s < 4; ++s)
        if (vals[s] > lv) { lv = vals[s]; pj = j0 + lane + (s << 6); }
    }
  }

  if (lane < Kq) {
    const int cbase = (row * T4 + t) * Kq + lane;
    candV[cbase] = myv;
    candI[cbase] = b * Nq + myj;           // global index
  }
}

// ---------------- stage 2: merge 80 candidates/row -> top-20 + softmax + out ----------------
// grid = BN/4 = 512 blocks, block = 256 (wave = row).
__global__ __launch_bounds__(256) void topk2_kernel(
    const float* __restrict__ candV, const int* __restrict__ candI,
    float* __restrict__ out) {
  const int row  = blockIdx.x * 4 + (threadIdx.x >> 6);
  const int lane = threadIdx.x & 63;
  const int cb   = row * CAND;

  float v0 = candV[cb + lane];
  int   i0 = candI[cb + lane];
  const bool has1 = (lane < CAND - 64);    // 16 extra slots
  float v1 = has1 ? candV[cb + 64 + lane] : NEGF;
  int   i1 = has1 ? candI[cb + 64 + lane] : 0x7FFFFFFF;

  float lv = v0; int li = i0;
  if (v1 > lv || (v1 == lv && i1 < li)) { lv = v1; li = i1; }

  float m0 = 0.f, ssum = 0.f, myv = 0.f;
  int myi = 0;
#pragma unroll 1
  for (int round = 0; round < Kq; ++round) {
    const float bv = wave_max(lv);
    const int isel = wave_min_i((lv == bv) ? li : 0x7FFFFFFF);
    if (round == 0) m0 = bv;
    ssum += __expf(0.4f * (bv - m0));
    if (lane == round) { myv = bv; myi = isel; }
    if (lv == bv && li == isel) {          // unique owner (indices unique)
      if (i0 == isel) v0 = NEGF;
      if (i1 == isel) v1 = NEGF;
      lv = v0; li = i0;
      if (v1 > lv || (v1 == lv && i1 < li)) { lv = v1; li = i1; }
    }
  }

  if (lane < Kq) {
    const float p = __expf(0.4f * (myv - m0)) / ssum;
    const int base = row * Kq + lane;
    out[base]            = (float)row;     // index_i
    out[BNK + base]      = (float)myi;     // index_j (already global)
    out[2 * BNK + base]  = p;              // attention
  }
}

extern "C" void kernel_launch(void* const* d_in, const int* in_sizes, int n_in,
                              void* d_out, int out_size, void* d_ws, size_t ws_size,
                              hipStream_t stream) {
  const float* x   = (const float*)d_in[0];
  const float* Wl  = (const float*)d_in[1];
  const float* bl  = (const float*)d_in[2];
  const float* Wr  = (const float*)d_in[3];
  const float* br  = (const float*)d_in[4];
  const float* att = (const float*)d_in[5];
  float* out = (float*)d_out;

  float* xl    = (float*)d_ws;                     // [B*N, E]
  float* xrP   = xl + (size_t)BN * Eq;             // [16][B*N][4] plane-major
  float* rdot  = xrP + (size_t)16 * BN * 4;        // [B*N]
  float* candV = rdot + (size_t)BN;                // [B*N][80]
  int*   candI = (int*)(candV + (size_t)BN * CAND);// [B*N][80]

  proj_kernel<<<BN, 128, 0, stream>>>(x, Wl, bl, Wr, br, att, xl, xrP, rdot);
  score1_kernel<<<(BN / 4) * T4, 256, 0, stream>>>(xl, xrP, rdot, att, candV, candI);
  topk2_kernel<<<BN / 4, 256, 0, stream>>>(candV, candI, out);
}